// Round 2
// 782.501 us; speedup vs baseline: 1.0344x; 1.0344x over previous
//
#include <hip/hip_runtime.h>
#include <hip/hip_fp16.h>

#define BUCKET_BITS 12
#define BUCKET_SIZE 4096           // atoms per bucket -> 16 KB LDS tile in reduce
#define NB 256                     // max buckets (n_atoms <= 1M)
#define PPB 8192                   // pairs per scatter block (32 KB LDS staging)
#define BLK_A 512                  // 512 thr, slim regs -> 4 blocks/CU = 32 waves
#define ITERS (PPB / 4 / BLK_A)    // int4 groups per thread = 4
#define RBLK 512
#define RSPLIT 4                   // sub-blocks per bucket in reduce
#define MOL_BLOCKS 64

// ---------------- fast path ----------------

__global__ void init_cursors(int* __restrict__ cur, int nbuckets, int cap) {
    int b = blockIdx.x * blockDim.x + threadIdx.x;
    if (b < nbuckets) cur[b] = b * cap;
}

// Block-level counting sort. Phase 0 fuses load+gather+divide+fp16-pack so
// only f4 (bucket/local ids) and packed entry words stay live across the
// barriers (~32 VGPRs) -> 64-VGPR budget is feasible at 32 waves/CU.
// pair_first/second/dist each read exactly ONCE from HBM.
// Entry = (local_atom_idx << 16) | fp16_bits(v)  -- 4 bytes.
__global__ __launch_bounds__(BLK_A, 8) void pair_scatter(
    const int4*   __restrict__ first4,
    const int4*   __restrict__ second4,
    const float4* __restrict__ dist4,
    const float*  __restrict__ charges,
    const float*  __restrict__ ecf_p,
    int* __restrict__ cur,
    unsigned* __restrict__ entries,
    int n_pairs4) {
    __shared__ unsigned stag[PPB];      // 32 KB
    __shared__ int hist[NB];
    __shared__ int lofs[NB + 1];
    __shared__ int gadj[NB];
    __shared__ int wsum[NB / 64];

    const int tid = threadIdx.x;
    const int base4 = blockIdx.x * (PPB / 4);
    const float ecf = *ecf_p;

    if (tid < NB) hist[tid] = 0;

    // phase 0: load pairs, gather charges, compute v, pack entries.
    // After this loop only f4 + ent are live (32 VGPRs).
    int4 f4[ITERS];
    unsigned ent[ITERS][4];
    #pragma unroll
    for (int it = 0; it < ITERS; ++it) {
        int g = base4 + it * BLK_A + tid;
        if (g < n_pairs4) {
            f4[it] = first4[g];
            int4   s = second4[g];
            float4 d = dist4[g];
            float c0 = charges[s.x];
            float c1 = charges[s.y];
            float c2 = charges[s.z];
            float c3 = charges[s.w];
            float v0 = ecf * c0 / d.x;
            float v1 = ecf * c1 / d.y;
            float v2 = ecf * c2 / d.z;
            float v3 = ecf * c3 / d.w;
            ent[it][0] = ((unsigned)(f4[it].x & (BUCKET_SIZE - 1)) << 16) |
                         (unsigned)__half_as_ushort(__float2half(v0));
            ent[it][1] = ((unsigned)(f4[it].y & (BUCKET_SIZE - 1)) << 16) |
                         (unsigned)__half_as_ushort(__float2half(v1));
            ent[it][2] = ((unsigned)(f4[it].z & (BUCKET_SIZE - 1)) << 16) |
                         (unsigned)__half_as_ushort(__float2half(v2));
            ent[it][3] = ((unsigned)(f4[it].w & (BUCKET_SIZE - 1)) << 16) |
                         (unsigned)__half_as_ushort(__float2half(v3));
        } else {
            f4[it] = make_int4(-1, -1, -1, -1);
            ent[it][0] = ent[it][1] = ent[it][2] = ent[it][3] = 0u;
        }
    }
    __syncthreads();   // hist zeroing visible

    // phase 1: histogram (bucket id = f >> 12, recomputed from registers)
    #pragma unroll
    for (int it = 0; it < ITERS; ++it) {
        if (f4[it].x >= 0) {
            atomicAdd(&hist[f4[it].x >> BUCKET_BITS], 1);
            atomicAdd(&hist[f4[it].y >> BUCKET_BITS], 1);
            atomicAdd(&hist[f4[it].z >> BUCKET_BITS], 1);
            atomicAdd(&hist[f4[it].w >> BUCKET_BITS], 1);
        }
    }
    __syncthreads();

    // phase 2: exclusive prefix scan over 256 buckets (shfl wave-scan)
    int cnt = 0, v = 0;
    if (tid < NB) {
        cnt = hist[tid];
        v = cnt;
        #pragma unroll
        for (int off = 1; off < 64; off <<= 1) {
            int n = __shfl_up(v, off);
            if ((tid & 63) >= off) v += n;
        }
        if ((tid & 63) == 63) wsum[tid >> 6] = v;
    }
    __syncthreads();
    if (tid == 0) {
        int r = 0;
        #pragma unroll
        for (int w = 0; w < NB / 64; ++w) { int t = wsum[w]; wsum[w] = r; r += t; }
    }
    __syncthreads();
    if (tid < NB) {
        int incl = v + wsum[tid >> 6];
        int excl = incl - cnt;
        lofs[tid + 1] = incl;
        if (tid == 0) lofs[0] = 0;
        // reserve this block's contiguous range in the bucket's global region
        if (cnt > 0) gadj[tid] = atomicAdd(&cur[tid], cnt) - excl;
        hist[tid] = excl;                 // reuse hist as local placement cursor
    }
    __syncthreads();

    // phase 3: place sorted-by-bucket into LDS staging
    #pragma unroll
    for (int it = 0; it < ITERS; ++it) {
        if (f4[it].x >= 0) {
            int p0 = atomicAdd(&hist[f4[it].x >> BUCKET_BITS], 1);
            stag[p0] = ent[it][0];
            int p1 = atomicAdd(&hist[f4[it].y >> BUCKET_BITS], 1);
            stag[p1] = ent[it][1];
            int p2 = atomicAdd(&hist[f4[it].z >> BUCKET_BITS], 1);
            stag[p2] = ent[it][2];
            int p3 = atomicAdd(&hist[f4[it].w >> BUCKET_BITS], 1);
            stag[p3] = ent[it][3];
        }
    }
    __syncthreads();

    // phase 4: coalesced flush; flat i -> bucket via binary search in lofs
    const int tot = lofs[NB];
    for (int i = tid; i < tot; i += BLK_A) {
        unsigned e = stag[i];
        int lo = 0, hi = NB - 1;
        #pragma unroll
        for (int s = 0; s < 8; ++s) {
            int mid = (lo + hi + 1) >> 1;
            if (lofs[mid] <= i) lo = mid; else hi = mid - 1;
        }
        entries[gadj[lo] + i] = e;
    }
}

// RSPLIT sub-blocks per bucket: each reduces a slice of the entry stream
// into a private LDS tile, then coalesced atomicAdd into pre-zeroed voltage.
__global__ __launch_bounds__(RBLK) void bucket_reduce(
    const unsigned* __restrict__ entries,
    const int* __restrict__ cur,
    float* __restrict__ voltage,
    int cap, int n_atoms) {
    __shared__ float volt[BUCKET_SIZE];
    const int b    = blockIdx.x / RSPLIT;
    const int part = blockIdx.x % RSPLIT;
    for (int i = threadIdx.x; i < BUCKET_SIZE; i += RBLK) volt[i] = 0.f;
    __syncthreads();
    const int start = b * cap;                // cap multiple of 4 -> 16B aligned
    const int cnt = cur[b] - start;
    const int cnt4 = cnt >> 2;
    const int chunk = (cnt4 + RSPLIT - 1) / RSPLIT;
    const int lo = part * chunk;
    const int hi = min(cnt4, lo + chunk);
    const uint4* e4p = (const uint4*)(entries + start);
    for (int i = lo + threadIdx.x; i < hi; i += RBLK) {
        uint4 e = e4p[i];
        atomicAdd(&volt[e.x >> 16], __half2float(__ushort_as_half((unsigned short)(e.x & 0xFFFFu))));
        atomicAdd(&volt[e.y >> 16], __half2float(__ushort_as_half((unsigned short)(e.y & 0xFFFFu))));
        atomicAdd(&volt[e.z >> 16], __half2float(__ushort_as_half((unsigned short)(e.z & 0xFFFFu))));
        atomicAdd(&volt[e.w >> 16], __half2float(__ushort_as_half((unsigned short)(e.w & 0xFFFFu))));
    }
    if (part == RSPLIT - 1) {
        for (int i = (cnt4 << 2) + threadIdx.x; i < cnt; i += RBLK) {
            unsigned e = entries[start + i];
            atomicAdd(&volt[e >> 16], __half2float(__ushort_as_half((unsigned short)(e & 0xFFFFu))));
        }
    }
    __syncthreads();
    const int abase = b << BUCKET_BITS;
    const int nat = min(BUCKET_SIZE, n_atoms - abase);
    for (int i = threadIdx.x; i < nat; i += RBLK)
        atomicAdd(&voltage[abase + i], volt[i]);
}

// Hierarchical molecule reduction: per-block LDS partials -> dense ws store.
__global__ __launch_bounds__(1024) void mol_partial(
    const float* __restrict__ charges,
    const float* __restrict__ voltage,
    const int*  __restrict__ mol_index,
    float* __restrict__ partials,
    int n_mol, int n_atoms) {
    extern __shared__ float smem[];
    for (int i = threadIdx.x; i < n_mol; i += blockDim.x) smem[i] = 0.f;
    __syncthreads();
    const int n4 = n_atoms >> 2;
    const int gid = blockIdx.x * blockDim.x + threadIdx.x;
    const int stride = gridDim.x * blockDim.x;
    const float4* c4p = (const float4*)charges;
    const float4* v4p = (const float4*)voltage;
    const int4*   m4p = (const int4*)mol_index;
    for (int i = gid; i < n4; i += stride) {
        float4 c = c4p[i]; float4 v = v4p[i]; int4 m = m4p[i];
        atomicAdd(&smem[m.x], 0.5f * v.x * c.x);
        atomicAdd(&smem[m.y], 0.5f * v.y * c.y);
        atomicAdd(&smem[m.z], 0.5f * v.z * c.z);
        atomicAdd(&smem[m.w], 0.5f * v.w * c.w);
    }
    for (int i = (n4 << 2) + gid; i < n_atoms; i += stride)
        atomicAdd(&smem[mol_index[i]], 0.5f * voltage[i] * charges[i]);
    __syncthreads();
    float* dst = partials + (size_t)blockIdx.x * n_mol;
    for (int i = threadIdx.x; i < n_mol; i += blockDim.x)
        dst[i] = smem[i];
}

__global__ void mol_final(const float* __restrict__ partials,
                          float* __restrict__ mol_out,
                          int n_mol, int nparts) {
    int m = blockIdx.x * blockDim.x + threadIdx.x;
    if (m >= n_mol) return;
    float s = 0.f;
    for (int p = 0; p < nparts; ++p) s += partials[(size_t)p * n_mol + m];
    mol_out[m] = s;
}

// ---------------- fallback path (direct atomics, known-correct) ----------------

__global__ void coulomb_pair_direct(const float* __restrict__ dist,
                                    const int*  __restrict__ first,
                                    const int*  __restrict__ second,
                                    const float* __restrict__ charges,
                                    const float* __restrict__ ecf_p,
                                    float* __restrict__ voltage,
                                    int n_pairs) {
    int p = blockIdx.x * blockDim.x + threadIdx.x;
    if (p >= n_pairs) return;
    float v = (*ecf_p) * charges[second[p]] / dist[p];
    atomicAdd(&voltage[first[p]], v);
}

__global__ void coulomb_atom_direct(const float* __restrict__ charges,
                                    const float* __restrict__ voltage,
                                    const int*  __restrict__ mol_index,
                                    float* __restrict__ mol_out,
                                    int n_atoms) {
    int a = blockIdx.x * blockDim.x + threadIdx.x;
    if (a >= n_atoms) return;
    atomicAdd(&mol_out[mol_index[a]], 0.5f * voltage[a] * charges[a]);
}

extern "C" void kernel_launch(void* const* d_in, const int* in_sizes, int n_in,
                              void* d_out, int out_size, void* d_ws, size_t ws_size,
                              hipStream_t stream) {
    const float* charges     = (const float*)d_in[0];
    const float* pair_dist   = (const float*)d_in[1];
    const int*   pair_first  = (const int*)d_in[2];
    const int*   pair_second = (const int*)d_in[3];
    const int*   mol_index   = (const int*)d_in[4];
    const float* ecf_p       = (const float*)d_in[6];

    const int n_atoms = in_sizes[0];
    const int n_pairs = in_sizes[1];
    const int n_mol   = out_size - n_atoms;

    float* mol_out = (float*)d_out;           // [n_mol]
    float* voltage = (float*)d_out + n_mol;   // [n_atoms]

    const int nbuckets = (n_atoms + BUCKET_SIZE - 1) >> BUCKET_BITS;
    long long capll = (long long)n_pairs / (nbuckets > 0 ? nbuckets : 1);
    capll += capll / 16 + 4096;               // >20 sigma headroom for uniform keys
    capll = (capll + 3) & ~3LL;               // 16B-align bucket bases
    long long tot_entries = capll * nbuckets;
    size_t entries_bytes = (size_t)tot_entries * sizeof(unsigned);
    size_t cur_off = (entries_bytes + 255) & ~(size_t)255;
    size_t mol_off = (cur_off + (size_t)nbuckets * sizeof(int) + 255) & ~(size_t)255;
    size_t need_base = cur_off + (size_t)nbuckets * sizeof(int);
    size_t need_mol  = mol_off + (size_t)MOL_BLOCKS * n_mol * sizeof(float);

    const bool mol_lds_ok = (size_t)n_mol * sizeof(float) <= 60 * 1024;
    const bool fast = (nbuckets >= 1) && (nbuckets <= NB) &&
                      (tot_entries < 0x7fffffffLL) &&
                      ((n_pairs & 3) == 0) &&
                      (need_base <= ws_size);
    const bool mol_hier = fast && mol_lds_ok && (need_mol <= ws_size);

    if (fast) {
        unsigned* entries = (unsigned*)d_ws;
        int* cur = (int*)((char*)d_ws + cur_off);
        const int cap = (int)capll;

        init_cursors<<<1, 256, 0, stream>>>(cur, nbuckets, cap);

        // bucket_reduce accumulates with atomics now -> pre-zero its output
        if (mol_hier) {
            hipMemsetAsync(voltage, 0, (size_t)n_atoms * sizeof(float), stream);
        } else {
            hipMemsetAsync(d_out, 0, (size_t)out_size * sizeof(float), stream);
        }

        const int n_pairs4 = n_pairs >> 2;
        const int nblocks = (n_pairs + PPB - 1) / PPB;
        pair_scatter<<<nblocks, BLK_A, 0, stream>>>(
            (const int4*)pair_first, (const int4*)pair_second,
            (const float4*)pair_dist, charges, ecf_p, cur, entries, n_pairs4);

        bucket_reduce<<<nbuckets * RSPLIT, RBLK, 0, stream>>>(
            entries, cur, voltage, cap, n_atoms);

        if (mol_hier) {
            float* partials = (float*)((char*)d_ws + mol_off);
            mol_partial<<<MOL_BLOCKS, 1024, n_mol * sizeof(float), stream>>>(
                charges, voltage, mol_index, partials, n_mol, n_atoms);
            mol_final<<<(n_mol + 255) / 256, 256, 0, stream>>>(
                partials, mol_out, n_mol, MOL_BLOCKS);
        } else {
            coulomb_atom_direct<<<(n_atoms + 255) / 256, 256, 0, stream>>>(
                charges, voltage, mol_index, mol_out, n_atoms);
        }
    } else {
        // fallback: direct global atomics (round-1 behavior)
        hipMemsetAsync(d_out, 0, (size_t)out_size * sizeof(float), stream);
        coulomb_pair_direct<<<(n_pairs + 255) / 256, 256, 0, stream>>>(
            pair_dist, pair_first, pair_second, charges, ecf_p, voltage, n_pairs);
        coulomb_atom_direct<<<(n_atoms + 255) / 256, 256, 0, stream>>>(
            charges, voltage, mol_index, mol_out, n_atoms);
    }
}

// Round 4
// 777.833 us; speedup vs baseline: 1.0406x; 1.0060x over previous
//
#include <hip/hip_runtime.h>
#include <hip/hip_fp16.h>

#define BUCKET_BITS 12
#define BUCKET_SIZE 4096           // atoms per bucket -> 16 KB LDS tile in reduce
#define NB 256                     // max buckets (n_atoms <= 1M)
#define PPB 8192                   // pairs per scatter block (32 KB LDS staging)
#define BLK_A 512                  // 512 thr; launch_bounds(512,4) -> 128 VGPR cap
#define ITERS (PPB / 4 / BLK_A)    // int4 groups per thread = 4
#define RBLK 512
#define RSPLIT 4                   // sub-blocks per bucket in reduce
#define MOL_BLOCKS 64

// ---------------- fast path ----------------

__global__ void init_cursors(int* __restrict__ cur, int nbuckets, int cap) {
    int b = blockIdx.x * blockDim.x + threadIdx.x;
    if (b < nbuckets) cur[b] = b * cap;
}

// Block-level counting sort, single atomic pass:
// phase 0 computes the packed entry AND grabs the element's within-bucket
// rank from the histogram atomic's return value. After the scan, placement
// is a pure LDS store at lofs[bucket]+rank (no second atomic pass).
// Live state across barriers: ent[16] + br[16] packed words ~= 32 VGPRs;
// launch_bounds(512,4) gives a 128-VGPR budget -> no scratch spills
// (R2's launch_bounds(512,8) forced VGPR=32 and spilled everything).
// Entry = (local_atom_idx << 16) | fp16_bits(v); br = (bucket << 16) | rank.
__global__ __launch_bounds__(BLK_A, 4) void pair_scatter(
    const int4*   __restrict__ first4,
    const int4*   __restrict__ second4,
    const float4* __restrict__ dist4,
    const float*  __restrict__ charges,
    const float*  __restrict__ ecf_p,
    int* __restrict__ cur,
    unsigned* __restrict__ entries,
    int n_pairs4) {
    __shared__ unsigned stag[PPB];      // 32 KB
    __shared__ int hist[NB];
    __shared__ int lofs[NB + 1];
    __shared__ int gadj[NB];
    __shared__ int wsum[NB / 64];

    const int tid = threadIdx.x;
    const int base4 = blockIdx.x * (PPB / 4);
    const float ecf = *ecf_p;

    if (tid < NB) hist[tid] = 0;
    __syncthreads();

    // phase 0: load pairs, gather charges, compute v, pack entry, take rank.
    unsigned ent[ITERS][4];
    int br[ITERS][4];
    #pragma unroll
    for (int it = 0; it < ITERS; ++it) {
        int g = base4 + it * BLK_A + tid;
        if (g < n_pairs4) {
            int4   f = first4[g];
            int4   s = second4[g];
            float4 d = dist4[g];
            float c0 = charges[s.x];
            float c1 = charges[s.y];
            float c2 = charges[s.z];
            float c3 = charges[s.w];
            float v0 = ecf * c0 / d.x;
            float v1 = ecf * c1 / d.y;
            float v2 = ecf * c2 / d.z;
            float v3 = ecf * c3 / d.w;
            ent[it][0] = ((unsigned)(f.x & (BUCKET_SIZE - 1)) << 16) |
                         (unsigned)__half_as_ushort(__float2half(v0));
            ent[it][1] = ((unsigned)(f.y & (BUCKET_SIZE - 1)) << 16) |
                         (unsigned)__half_as_ushort(__float2half(v1));
            ent[it][2] = ((unsigned)(f.z & (BUCKET_SIZE - 1)) << 16) |
                         (unsigned)__half_as_ushort(__float2half(v2));
            ent[it][3] = ((unsigned)(f.w & (BUCKET_SIZE - 1)) << 16) |
                         (unsigned)__half_as_ushort(__float2half(v3));
            int b0 = f.x >> BUCKET_BITS;
            int b1 = f.y >> BUCKET_BITS;
            int b2 = f.z >> BUCKET_BITS;
            int b3 = f.w >> BUCKET_BITS;
            br[it][0] = (b0 << 16) | atomicAdd(&hist[b0], 1);
            br[it][1] = (b1 << 16) | atomicAdd(&hist[b1], 1);
            br[it][2] = (b2 << 16) | atomicAdd(&hist[b2], 1);
            br[it][3] = (b3 << 16) | atomicAdd(&hist[b3], 1);
        } else {
            br[it][0] = br[it][1] = br[it][2] = br[it][3] = -1;
            ent[it][0] = ent[it][1] = ent[it][2] = ent[it][3] = 0u;
        }
    }
    __syncthreads();

    // phase 1: exclusive prefix scan over 256 buckets (shfl wave-scan)
    int cnt = 0, v = 0;
    if (tid < NB) {
        cnt = hist[tid];
        v = cnt;
        #pragma unroll
        for (int off = 1; off < 64; off <<= 1) {
            int n = __shfl_up(v, off);
            if ((tid & 63) >= off) v += n;
        }
        if ((tid & 63) == 63) wsum[tid >> 6] = v;
    }
    __syncthreads();
    if (tid == 0) {
        int r = 0;
        #pragma unroll
        for (int w = 0; w < NB / 64; ++w) { int t = wsum[w]; wsum[w] = r; r += t; }
    }
    __syncthreads();
    if (tid < NB) {
        int incl = v + wsum[tid >> 6];
        int excl = incl - cnt;
        lofs[tid + 1] = incl;
        if (tid == 0) lofs[0] = 0;
        // reserve this block's contiguous range in the bucket's global region
        if (cnt > 0) gadj[tid] = atomicAdd(&cur[tid], cnt) - excl;
    }
    __syncthreads();

    // phase 2: place sorted-by-bucket into LDS staging (pure read+store)
    #pragma unroll
    for (int it = 0; it < ITERS; ++it) {
        #pragma unroll
        for (int j = 0; j < 4; ++j) {
            int w = br[it][j];
            if (w >= 0) stag[lofs[w >> 16] + (w & 0xFFFF)] = ent[it][j];
        }
    }
    __syncthreads();

    // phase 3: coalesced flush; flat i -> bucket via binary search in lofs
    const int tot = lofs[NB];
    for (int i = tid; i < tot; i += BLK_A) {
        unsigned e = stag[i];
        int lo = 0, hi = NB - 1;
        #pragma unroll
        for (int s = 0; s < 8; ++s) {
            int mid = (lo + hi + 1) >> 1;
            if (lofs[mid] <= i) lo = mid; else hi = mid - 1;
        }
        entries[gadj[lo] + i] = e;
    }
}

// RSPLIT sub-blocks per bucket: each reduces a slice of the entry stream
// into a private LDS tile, then coalesced atomicAdd into pre-zeroed voltage.
__global__ __launch_bounds__(RBLK) void bucket_reduce(
    const unsigned* __restrict__ entries,
    const int* __restrict__ cur,
    float* __restrict__ voltage,
    int cap, int n_atoms) {
    __shared__ float volt[BUCKET_SIZE];
    const int b    = blockIdx.x / RSPLIT;
    const int part = blockIdx.x % RSPLIT;
    for (int i = threadIdx.x; i < BUCKET_SIZE; i += RBLK) volt[i] = 0.f;
    __syncthreads();
    const int start = b * cap;                // cap multiple of 4 -> 16B aligned
    const int cnt = cur[b] - start;
    const int cnt4 = cnt >> 2;
    const int chunk = (cnt4 + RSPLIT - 1) / RSPLIT;
    const int lo = part * chunk;
    const int hi = min(cnt4, lo + chunk);
    const uint4* e4p = (const uint4*)(entries + start);
    for (int i = lo + threadIdx.x; i < hi; i += RBLK) {
        uint4 e = e4p[i];
        atomicAdd(&volt[e.x >> 16], __half2float(__ushort_as_half((unsigned short)(e.x & 0xFFFFu))));
        atomicAdd(&volt[e.y >> 16], __half2float(__ushort_as_half((unsigned short)(e.y & 0xFFFFu))));
        atomicAdd(&volt[e.z >> 16], __half2float(__ushort_as_half((unsigned short)(e.z & 0xFFFFu))));
        atomicAdd(&volt[e.w >> 16], __half2float(__ushort_as_half((unsigned short)(e.w & 0xFFFFu))));
    }
    if (part == RSPLIT - 1) {
        for (int i = (cnt4 << 2) + threadIdx.x; i < cnt; i += RBLK) {
            unsigned e = entries[start + i];
            atomicAdd(&volt[e >> 16], __half2float(__ushort_as_half((unsigned short)(e & 0xFFFFu))));
        }
    }
    __syncthreads();
    const int abase = b << BUCKET_BITS;
    const int nat = min(BUCKET_SIZE, n_atoms - abase);
    for (int i = threadIdx.x; i < nat; i += RBLK)
        atomicAdd(&voltage[abase + i], volt[i]);
}

// Hierarchical molecule reduction: per-block LDS partials -> dense ws store.
__global__ __launch_bounds__(1024) void mol_partial(
    const float* __restrict__ charges,
    const float* __restrict__ voltage,
    const int*  __restrict__ mol_index,
    float* __restrict__ partials,
    int n_mol, int n_atoms) {
    extern __shared__ float smem[];
    for (int i = threadIdx.x; i < n_mol; i += blockDim.x) smem[i] = 0.f;
    __syncthreads();
    const int n4 = n_atoms >> 2;
    const int gid = blockIdx.x * blockDim.x + threadIdx.x;
    const int stride = gridDim.x * blockDim.x;
    const float4* c4p = (const float4*)charges;
    const float4* v4p = (const float4*)voltage;
    const int4*   m4p = (const int4*)mol_index;
    for (int i = gid; i < n4; i += stride) {
        float4 c = c4p[i]; float4 v = v4p[i]; int4 m = m4p[i];
        atomicAdd(&smem[m.x], 0.5f * v.x * c.x);
        atomicAdd(&smem[m.y], 0.5f * v.y * c.y);
        atomicAdd(&smem[m.z], 0.5f * v.z * c.z);
        atomicAdd(&smem[m.w], 0.5f * v.w * c.w);
    }
    for (int i = (n4 << 2) + gid; i < n_atoms; i += stride)
        atomicAdd(&smem[mol_index[i]], 0.5f * voltage[i] * charges[i]);
    __syncthreads();
    float* dst = partials + (size_t)blockIdx.x * n_mol;
    for (int i = threadIdx.x; i < n_mol; i += blockDim.x)
        dst[i] = smem[i];
}

__global__ void mol_final(const float* __restrict__ partials,
                          float* __restrict__ mol_out,
                          int n_mol, int nparts) {
    int m = blockIdx.x * blockDim.x + threadIdx.x;
    if (m >= n_mol) return;
    float s = 0.f;
    for (int p = 0; p < nparts; ++p) s += partials[(size_t)p * n_mol + m];
    mol_out[m] = s;
}

// ---------------- fallback path (direct atomics, known-correct) ----------------

__global__ void coulomb_pair_direct(const float* __restrict__ dist,
                                    const int*  __restrict__ first,
                                    const int*  __restrict__ second,
                                    const float* __restrict__ charges,
                                    const float* __restrict__ ecf_p,
                                    float* __restrict__ voltage,
                                    int n_pairs) {
    int p = blockIdx.x * blockDim.x + threadIdx.x;
    if (p >= n_pairs) return;
    float v = (*ecf_p) * charges[second[p]] / dist[p];
    atomicAdd(&voltage[first[p]], v);
}

__global__ void coulomb_atom_direct(const float* __restrict__ charges,
                                    const float* __restrict__ voltage,
                                    const int*  __restrict__ mol_index,
                                    float* __restrict__ mol_out,
                                    int n_atoms) {
    int a = blockIdx.x * blockDim.x + threadIdx.x;
    if (a >= n_atoms) return;
    atomicAdd(&mol_out[mol_index[a]], 0.5f * voltage[a] * charges[a]);
}

extern "C" void kernel_launch(void* const* d_in, const int* in_sizes, int n_in,
                              void* d_out, int out_size, void* d_ws, size_t ws_size,
                              hipStream_t stream) {
    const float* charges     = (const float*)d_in[0];
    const float* pair_dist   = (const float*)d_in[1];
    const int*   pair_first  = (const int*)d_in[2];
    const int*   pair_second = (const int*)d_in[3];
    const int*   mol_index   = (const int*)d_in[4];
    const float* ecf_p       = (const float*)d_in[6];

    const int n_atoms = in_sizes[0];
    const int n_pairs = in_sizes[1];
    const int n_mol   = out_size - n_atoms;

    float* mol_out = (float*)d_out;           // [n_mol]
    float* voltage = (float*)d_out + n_mol;   // [n_atoms]

    const int nbuckets = (n_atoms + BUCKET_SIZE - 1) >> BUCKET_BITS;
    long long capll = (long long)n_pairs / (nbuckets > 0 ? nbuckets : 1);
    capll += capll / 16 + 4096;               // >20 sigma headroom for uniform keys
    capll = (capll + 3) & ~3LL;               // 16B-align bucket bases
    long long tot_entries = capll * nbuckets;
    size_t entries_bytes = (size_t)tot_entries * sizeof(unsigned);
    size_t cur_off = (entries_bytes + 255) & ~(size_t)255;
    size_t mol_off = (cur_off + (size_t)nbuckets * sizeof(int) + 255) & ~(size_t)255;
    size_t need_base = cur_off + (size_t)nbuckets * sizeof(int);
    size_t need_mol  = mol_off + (size_t)MOL_BLOCKS * n_mol * sizeof(float);

    const bool mol_lds_ok = (size_t)n_mol * sizeof(float) <= 60 * 1024;
    const bool fast = (nbuckets >= 1) && (nbuckets <= NB) &&
                      (tot_entries < 0x7fffffffLL) &&
                      ((n_pairs & 3) == 0) &&
                      (need_base <= ws_size);
    const bool mol_hier = fast && mol_lds_ok && (need_mol <= ws_size);

    if (fast) {
        unsigned* entries = (unsigned*)d_ws;
        int* cur = (int*)((char*)d_ws + cur_off);
        const int cap = (int)capll;

        init_cursors<<<1, 256, 0, stream>>>(cur, nbuckets, cap);

        // bucket_reduce accumulates with atomics -> pre-zero its output
        if (mol_hier) {
            hipMemsetAsync(voltage, 0, (size_t)n_atoms * sizeof(float), stream);
        } else {
            hipMemsetAsync(d_out, 0, (size_t)out_size * sizeof(float), stream);
        }

        const int n_pairs4 = n_pairs >> 2;
        const int nblocks = (n_pairs + PPB - 1) / PPB;
        pair_scatter<<<nblocks, BLK_A, 0, stream>>>(
            (const int4*)pair_first, (const int4*)pair_second,
            (const float4*)pair_dist, charges, ecf_p, cur, entries, n_pairs4);

        bucket_reduce<<<nbuckets * RSPLIT, RBLK, 0, stream>>>(
            entries, cur, voltage, cap, n_atoms);

        if (mol_hier) {
            float* partials = (float*)((char*)d_ws + mol_off);
            mol_partial<<<MOL_BLOCKS, 1024, n_mol * sizeof(float), stream>>>(
                charges, voltage, mol_index, partials, n_mol, n_atoms);
            mol_final<<<(n_mol + 255) / 256, 256, 0, stream>>>(
                partials, mol_out, n_mol, MOL_BLOCKS);
        } else {
            coulomb_atom_direct<<<(n_atoms + 255) / 256, 256, 0, stream>>>(
                charges, voltage, mol_index, mol_out, n_atoms);
        }
    } else {
        // fallback: direct global atomics (round-1 behavior)
        hipMemsetAsync(d_out, 0, (size_t)out_size * sizeof(float), stream);
        coulomb_pair_direct<<<(n_pairs + 255) / 256, 256, 0, stream>>>(
            pair_dist, pair_first, pair_second, charges, ecf_p, voltage, n_pairs);
        coulomb_atom_direct<<<(n_atoms + 255) / 256, 256, 0, stream>>>(
            charges, voltage, mol_index, mol_out, n_atoms);
    }
}